// Round 8
// baseline (191.514 us; speedup 1.0000x reference)
//
#include <hip/hip_runtime.h>

// Gated SPN, reverse scan over W:
//   h(i,t) = a*x + g1*h(i-1,t+1) + g2*h(i,t+1) + g3*h(i+1,t+1), a = 1-g1-g2-g3
//
// r8 = r7 (WT=32 cols, fp16-packed coeff tile, per-wave 16-row halo cones,
// 2 W-chunks x 128 slices = 256 blocks) + register-pressure fix:
// hv[16] per 16-step half (stores after each half) instead of hv[32] per
// tile. Peak pressure ~105 VGPR <= 128, so the compiler can keep the next
// tile's 16 global loads issued EARLY (overlapped with the scan) without
// hitting the 128-reg occupancy cliff that r7 dodged by sinking the loads
// (observed VGPR=64 -> no memory/compute overlap, 14.5 GB/s/CU issued).

#define HH 512
#define WW 512
#define WT 32
#define NT 1024            // 16 waves
#define ROWSP 545          // half4 row pitch: 16 halo + 512 + 16 halo + 1 pad
#define HLN 544

typedef _Float16 half4_t __attribute__((ext_vector_type(4)));

struct Regs { float4 x[4], g1[4], g2[4], g3[4]; };   // 4 rounds x 128 rows

__device__ __forceinline__ float dpp_prev(float v) {   // lane i <- lane i-1
    return __int_as_float(__builtin_amdgcn_update_dpp(
        0, __float_as_int(v), 0x138, 0xf, 0xf, false)); // wave_shr:1
}
__device__ __forceinline__ float dpp_next(float v) {   // lane i <- lane i+1
    return __int_as_float(__builtin_amdgcn_update_dpp(
        0, __float_as_int(v), 0x130, 0xf, 0xf, false)); // wave_shl:1
}

__device__ __forceinline__ void issue_loads(const float* __restrict__ Xp,
                                            const float* __restrict__ G1p,
                                            const float* __restrict__ G2p,
                                            const float* __restrict__ G3p,
                                            int w0, int lrow0, int lq, Regs& R)
{
    #pragma unroll
    for (int j = 0; j < 4; ++j) {
        const size_t off = (size_t)(lrow0 + j * 128) * WW + (size_t)(w0 + lq * 4);
        R.x[j]  = *(const float4*)(Xp  + off);
        R.g1[j] = *(const float4*)(G1p + off);
        R.g2[j] = *(const float4*)(G2p + off);
        R.g3[j] = *(const float4*)(G3p + off);
    }
}

__device__ __forceinline__ void norm_store(half4_t* __restrict__ tile, int w, int r,
                                           float xx, float g1, float g2, float g3)
{
    const float sa = fabsf(g1) + fabsf(g2) + fabsf(g3);
    const float sc = (sa >= 1.0f) ? (1.0f / sa) : 1.0f;
    const float n1 = g1 * sc, n2 = g2 * sc, n3 = g3 * sc;
    const float a  = 1.0f - n1 - n2 - n3;
    half4_t v;
    v.x = (_Float16)(a * xx);
    v.y = (_Float16)n1;
    v.z = (_Float16)n2;
    v.w = (_Float16)n3;
    tile[w * ROWSP + (r + 16)] = v;
}

__global__ __launch_bounds__(NT, 4) void spn_kernel(
    const float* __restrict__ X, const float* __restrict__ G1,
    const float* __restrict__ G2, const float* __restrict__ G3,
    float* __restrict__ OUT)
{
    extern __shared__ char smem[];
    half4_t* tile = (half4_t*)smem;                                        // [WT][ROWSP]
    float*   hl0  = (float*)(smem + (size_t)WT * ROWSP * sizeof(half4_t)); // [HLN] x2
    float*   hl1  = hl0 + HLN;

    const int tid  = threadIdx.x;
    const int wv   = tid >> 6;
    const int lane = tid & 63;
    const int cidx = 32 * wv + lane;        // cone row + 16, in [0, 544)
    const int row  = cidx - 16;             // cone row in [-16, 528)
    const bool owned = (lane >= 16) && (lane < 48);
    const int lrow0 = tid >> 3;             // 8 lanes per row (128B), 4 rounds (+128j)
    const int lq    = tid & 7;              // 16B eighth of the 128B row segment

    const int slice = blockIdx.x >> 1;
    const int ch    = blockIdx.x & 1;
    const int cend       = ch ? WW : 288;   // scan region right edge
    const int ntiles     = ch ? 8 : 9;      // 32-col tiles
    const int warm_tiles = ch ? 0 : 1;      // ch0's first tile is warmup

    const size_t base = (size_t)slice * (size_t)(HH * WW);
    const float* Xp  = X  + base;
    const float* G1p = G1 + base;
    const float* G2p = G2 + base;
    const float* G3p = G3 + base;
    float* Op = OUT + base;

    // zero tile halo rows (32 w-slots x 16 rows each side) + h-lines
    if (tid < 512) {
        const int w = tid >> 4, rr = tid & 15;
        half4_t z; z.x = (_Float16)0; z.y = (_Float16)0; z.z = (_Float16)0; z.w = (_Float16)0;
        tile[w * ROWSP + rr]       = z;    // rows -16..-1
        tile[w * ROWSP + 528 + rr] = z;    // rows 512..527
    }
    if (tid < HLN) { hl0[tid] = 0.0f; hl1[tid] = 0.0f; }

    Regs R;
    issue_loads(Xp, G1p, G2p, G3p, cend - WT, lrow0, lq, R);

    for (int t = 0; t < ntiles; ++t) {
        const int w0 = cend - WT * (t + 1);
        const bool emit = (t >= warm_tiles);

        // ---- stage current regs -> fp16 LDS tile ----
        #pragma unroll
        for (int j = 0; j < 4; ++j) {
            const int r  = lrow0 + j * 128;
            const int wb = lq * 4;
            norm_store(tile, wb + 0, r, R.x[j].x, R.g1[j].x, R.g2[j].x, R.g3[j].x);
            norm_store(tile, wb + 1, r, R.x[j].y, R.g1[j].y, R.g2[j].y, R.g3[j].y);
            norm_store(tile, wb + 2, r, R.x[j].z, R.g1[j].z, R.g2[j].z, R.g3[j].z);
            norm_store(tile, wb + 3, r, R.x[j].w, R.g1[j].w, R.g2[j].w, R.g3[j].w);
        }

        // ---- issue next tile's loads; in flight across both scan halves ----
        if (t + 1 < ntiles)
            issue_loads(Xp, G1p, G2p, G3p, w0 - WT, lrow0, lq, R);

        __syncthreads();   // tile visible (also protects hl0 from last iter)

        float hv[16];

        // ---- half A: 16 barrier-free steps, cols w0+31 .. w0+16 ----
        {
            float h = hl0[cidx];
            #pragma unroll
            for (int s = 0; s < 16; ++s) {
                const int q = 15 - s;
                const half4_t v = tile[(16 + q) * ROWSP + cidx];
                const float hu = dpp_prev(h);
                const float hd = dpp_next(h);
                h = fmaf((float)v.y, hu,
                    fmaf((float)v.z, h,
                    fmaf((float)v.w, hd, (float)v.x)));
                hv[q] = h;
            }
            if (owned) hl1[cidx] = h;   // re-anchor line for half B
        }
        // store half A (cols w0+16 .. w0+31): 64B contiguous per row
        if (owned && emit) {
            #pragma unroll
            for (int j = 0; j < 4; ++j) {
                const float4 o = make_float4(hv[4 * j + 0], hv[4 * j + 1],
                                             hv[4 * j + 2], hv[4 * j + 3]);
                *(float4*)(Op + (size_t)row * WW + (size_t)(w0 + 16 + 4 * j)) = o;
            }
        }
        __syncthreads();   // hl1 visible

        // ---- half B: 16 barrier-free steps, cols w0+15 .. w0 ----
        {
            float h = hl1[cidx];
            #pragma unroll
            for (int s = 0; s < 16; ++s) {
                const int q = 15 - s;
                const half4_t v = tile[q * ROWSP + cidx];
                const float hu = dpp_prev(h);
                const float hd = dpp_next(h);
                h = fmaf((float)v.y, hu,
                    fmaf((float)v.z, h,
                    fmaf((float)v.w, hd, (float)v.x)));
                hv[q] = h;
            }
            if (owned) hl0[cidx] = h;   // state for next tile
        }
        // store half B (cols w0 .. w0+15)
        if (owned && emit) {
            #pragma unroll
            for (int j = 0; j < 4; ++j) {
                const float4 o = make_float4(hv[4 * j + 0], hv[4 * j + 1],
                                             hv[4 * j + 2], hv[4 * j + 3]);
                *(float4*)(Op + (size_t)row * WW + (size_t)(w0 + 4 * j)) = o;
            }
        }
        __syncthreads();   // protect tile rewrite + hl0 publish
    }
}

extern "C" void kernel_launch(void* const* d_in, const int* in_sizes, int n_in,
                              void* d_out, int out_size, void* d_ws, size_t ws_size,
                              hipStream_t stream) {
    const float* X  = (const float*)d_in[0];
    const float* G1 = (const float*)d_in[1];
    const float* G2 = (const float*)d_in[2];
    const float* G3 = (const float*)d_in[3];
    float* OUT = (float*)d_out;

    const int nblocks = 4 * 32 * 2;   // 128 slices x 2 W-chunks = 256 = #CUs
    const size_t smem = (size_t)WT * ROWSP * sizeof(half4_t) + 2 * HLN * sizeof(float);

    (void)hipFuncSetAttribute((const void*)spn_kernel,
                              hipFuncAttributeMaxDynamicSharedMemorySize, (int)smem);

    spn_kernel<<<nblocks, NT, smem, stream>>>(X, G1, G2, G3, OUT);
}

// Round 10
// 155.070 us; speedup vs baseline: 1.2350x; 1.2350x over previous
//
#include <hip/hip_runtime.h>

// Gated SPN, reverse scan over W:
//   h(i,t) = a*x + g1*h(i-1,t+1) + g2*h(i,t+1) + g3*h(i+1,t+1), a = 1-g1-g2-g3
//
// r10 = r7 structure (WT=32 cols, fp16-packed coeff tile, per-wave 16-row
// halo cones, 2 W-chunks x 128 slices = 256 blocks = 1/CU) + non-draining
// barriers: raw s_barrier with lgkmcnt(0) only (8-phase-template primitive,
// verified on gfx950: raw s_barrier does NOT force vmcnt(0)). Next-tile
// global loads are plain tracked loads issued right after the post-stage
// barrier; they stay in flight across scan+stores and are waited (by the
// compiler's exact vmcnt) only at the next tile's staging reads.

#define HH 512
#define WW 512
#define WT 32
#define NT 1024            // 16 waves
#define ROWSP 545          // half4 row pitch: 16 halo + 512 + 16 halo + 1 pad
#define HLN 544

typedef _Float16 half4_t __attribute__((ext_vector_type(4)));

struct Regs { float4 x[4], g1[4], g2[4], g3[4]; };   // 4 rounds x 128 rows

__device__ __forceinline__ float dpp_prev(float v) {   // lane i <- lane i-1
    return __int_as_float(__builtin_amdgcn_update_dpp(
        0, __float_as_int(v), 0x138, 0xf, 0xf, false)); // wave_shr:1
}
__device__ __forceinline__ float dpp_next(float v) {   // lane i <- lane i+1
    return __int_as_float(__builtin_amdgcn_update_dpp(
        0, __float_as_int(v), 0x130, 0xf, 0xf, false)); // wave_shl:1
}

// LDS-only barrier: drains lgkm (ds_write visibility) but leaves vmem loads
// in flight. sched_barrier(0) stops any code motion across it (rule #18).
__device__ __forceinline__ void lds_barrier() {
    asm volatile("s_waitcnt lgkmcnt(0)" ::: "memory");
    __builtin_amdgcn_s_barrier();
    __builtin_amdgcn_sched_barrier(0);
}

__device__ __forceinline__ void issue_loads(const float* __restrict__ Xp,
                                            const float* __restrict__ G1p,
                                            const float* __restrict__ G2p,
                                            const float* __restrict__ G3p,
                                            int w0, int lrow0, int lq, Regs& R)
{
    #pragma unroll
    for (int j = 0; j < 4; ++j) {
        const size_t off = (size_t)(lrow0 + j * 128) * WW + (size_t)(w0 + lq * 4);
        R.x[j]  = *(const float4*)(Xp  + off);
        R.g1[j] = *(const float4*)(G1p + off);
        R.g2[j] = *(const float4*)(G2p + off);
        R.g3[j] = *(const float4*)(G3p + off);
    }
}

__device__ __forceinline__ void norm_store(half4_t* __restrict__ tile, int w, int r,
                                           float xx, float g1, float g2, float g3)
{
    const float sa = fabsf(g1) + fabsf(g2) + fabsf(g3);
    const float sc = (sa >= 1.0f) ? (1.0f / sa) : 1.0f;
    const float n1 = g1 * sc, n2 = g2 * sc, n3 = g3 * sc;
    const float a  = 1.0f - n1 - n2 - n3;
    half4_t v;
    v.x = (_Float16)(a * xx);
    v.y = (_Float16)n1;
    v.z = (_Float16)n2;
    v.w = (_Float16)n3;
    tile[w * ROWSP + (r + 16)] = v;
}

__global__ __launch_bounds__(NT, 4) void spn_kernel(
    const float* __restrict__ X, const float* __restrict__ G1,
    const float* __restrict__ G2, const float* __restrict__ G3,
    float* __restrict__ OUT)
{
    extern __shared__ char smem[];
    half4_t* tile = (half4_t*)smem;                                        // [WT][ROWSP]
    float*   hl0  = (float*)(smem + (size_t)WT * ROWSP * sizeof(half4_t)); // [HLN] x2
    float*   hl1  = hl0 + HLN;

    const int tid  = threadIdx.x;
    const int wv   = tid >> 6;
    const int lane = tid & 63;
    const int cidx = 32 * wv + lane;        // cone row + 16, in [0, 544)
    const int row  = cidx - 16;             // cone row in [-16, 528)
    const bool owned = (lane >= 16) && (lane < 48);
    const int lrow0 = tid >> 3;             // 8 lanes per row (128B), 4 rounds (+128j)
    const int lq    = tid & 7;              // 16B eighth of the 128B row segment

    const int slice = blockIdx.x >> 1;
    const int ch    = blockIdx.x & 1;
    const int cend       = ch ? WW : 288;   // scan region right edge
    const int ntiles     = ch ? 8 : 9;      // 32-col tiles
    const int warm_tiles = ch ? 0 : 1;      // ch0's first tile is warmup

    const size_t base = (size_t)slice * (size_t)(HH * WW);
    const float* Xp  = X  + base;
    const float* G1p = G1 + base;
    const float* G2p = G2 + base;
    const float* G3p = G3 + base;
    float* Op = OUT + base;

    // zero tile halo rows (32 w-slots x 16 rows each side) + h-lines;
    // visible at the first staging barrier
    if (tid < 512) {
        const int w = tid >> 4, rr = tid & 15;
        half4_t z; z.x = (_Float16)0; z.y = (_Float16)0; z.z = (_Float16)0; z.w = (_Float16)0;
        tile[w * ROWSP + rr]       = z;    // rows -16..-1
        tile[w * ROWSP + 528 + rr] = z;    // rows 512..527
    }
    if (tid < HLN) { hl0[tid] = 0.0f; hl1[tid] = 0.0f; }

    Regs R;
    issue_loads(Xp, G1p, G2p, G3p, cend - WT, lrow0, lq, R);

    for (int t = 0; t < ntiles; ++t) {
        const int w0 = cend - WT * (t + 1);
        const bool emit = (t >= warm_tiles);

        // ---- stage current regs -> fp16 LDS tile ----
        // (compiler inserts the exact vmcnt wait for R's loads right here)
        #pragma unroll
        for (int j = 0; j < 4; ++j) {
            const int r  = lrow0 + j * 128;
            const int wb = lq * 4;
            norm_store(tile, wb + 0, r, R.x[j].x, R.g1[j].x, R.g2[j].x, R.g3[j].x);
            norm_store(tile, wb + 1, r, R.x[j].y, R.g1[j].y, R.g2[j].y, R.g3[j].y);
            norm_store(tile, wb + 2, r, R.x[j].z, R.g1[j].z, R.g2[j].z, R.g3[j].z);
            norm_store(tile, wb + 3, r, R.x[j].w, R.g1[j].w, R.g2[j].w, R.g3[j].w);
        }
        lds_barrier();   // tile visible; vmem NOT drained

        // ---- issue next tile's loads: fly over scan A + B + stores ----
        if (t + 1 < ntiles)
            issue_loads(Xp, G1p, G2p, G3p, w0 - WT, lrow0, lq, R);
        __builtin_amdgcn_sched_barrier(0);   // pin issue point (no sinking)

        float hv[WT];

        // ---- half A: 16 barrier-free steps, cols w0+31 .. w0+16 ----
        {
            float h = hl0[cidx];
            #pragma unroll
            for (int s = 0; s < 16; ++s) {
                const int q = 31 - s;
                const half4_t v = tile[q * ROWSP + cidx];
                const float hu = dpp_prev(h);
                const float hd = dpp_next(h);
                h = fmaf((float)v.y, hu,
                    fmaf((float)v.z, h,
                    fmaf((float)v.w, hd, (float)v.x)));
                hv[q] = h;
            }
            if (owned) hl1[cidx] = h;   // re-anchor line for half B
        }
        lds_barrier();   // hl1 visible

        // ---- half B: 16 barrier-free steps, cols w0+15 .. w0 ----
        {
            float h = hl1[cidx];
            #pragma unroll
            for (int s = 0; s < 16; ++s) {
                const int q = 15 - s;
                const half4_t v = tile[q * ROWSP + cidx];
                const float hu = dpp_prev(h);
                const float hd = dpp_next(h);
                h = fmaf((float)v.y, hu,
                    fmaf((float)v.z, h,
                    fmaf((float)v.w, hd, (float)v.x)));
                hv[q] = h;
            }
            if (owned) hl0[cidx] = h;   // state for next tile
        }

        // ---- owned lanes: 128B contiguous stores (skip warmup tiles) ----
        if (owned && emit) {
            #pragma unroll
            for (int j = 0; j < 8; ++j) {
                const float4 o = make_float4(hv[4 * j + 0], hv[4 * j + 1],
                                             hv[4 * j + 2], hv[4 * j + 3]);
                *(float4*)(Op + (size_t)row * WW + (size_t)(w0 + 4 * j)) = o;
            }
        }
        lds_barrier();   // hl0 publish visible + tile rewrite safe
    }
}

extern "C" void kernel_launch(void* const* d_in, const int* in_sizes, int n_in,
                              void* d_out, int out_size, void* d_ws, size_t ws_size,
                              hipStream_t stream) {
    const float* X  = (const float*)d_in[0];
    const float* G1 = (const float*)d_in[1];
    const float* G2 = (const float*)d_in[2];
    const float* G3 = (const float*)d_in[3];
    float* OUT = (float*)d_out;

    const int nblocks = 4 * 32 * 2;   // 128 slices x 2 W-chunks = 256 = #CUs
    const size_t smem = (size_t)WT * ROWSP * sizeof(half4_t) + 2 * HLN * sizeof(float);

    (void)hipFuncSetAttribute((const void*)spn_kernel,
                              hipFuncAttributeMaxDynamicSharedMemorySize, (int)smem);

    spn_kernel<<<nblocks, NT, smem, stream>>>(X, G1, G2, G3, OUT);
}